// Round 4
// baseline (9929.638 us; speedup 1.0000x reference)
//
#include <hip/hip_runtime.h>
#include <hip/hip_bf16.h>
#include <math.h>

// SpatialTemporalModel: GCN(2-layer) x24 -> LSTM(128) -> MLP head.
// Round 4: (a) fused per-step back half: layer-2 gather -> h2 MFMA -> LSTM MFMA
// in ONE kernel, v/h2 never hit HBM (v parks in the LSTM staging LDS at kc8..11,
// h2 MFMA writes kc0..3, h_prev then overwrites kc8..11);
// (b) hbuf stored as packed bf16 hi|lo u32 (no re-split on staging);
// (c) CSR fill in 2 dst-range passes so the col write window is L2-resident.

typedef short s16x8 __attribute__((ext_vector_type(8)));
typedef float f32x16 __attribute__((ext_vector_type(16)));
typedef unsigned long long u64;
union AF { s16x8 v; u64 q[2]; };

__device__ __forceinline__ float sigf(float x) { return 1.f / (1.f + __expf(-x)); }
__device__ __forceinline__ float tanhfast(float x) { return 1.f - 2.f / (1.f + __expf(2.f * x)); }

// round-to-nearest-even f32 -> bf16 bits
__device__ __forceinline__ unsigned bfr(float x) {
    union { float f; unsigned u; } c; c.f = x;
    return (c.u + 0x7fffu + ((c.u >> 16) & 1u)) >> 16;
}
__device__ __forceinline__ void bsplit(float x, unsigned short& hi, unsigned short& lo) {
    unsigned h = bfr(x);
    union { unsigned u; float f; } hf; hf.u = h << 16;
    hi = (unsigned short)h;
    lo = (unsigned short)bfr(x - hf.f);
}
__device__ __forceinline__ float bf2f(unsigned short b) {
    union { unsigned u; float f; } c; c.u = ((unsigned)b) << 16;
    return c.f;
}

// ---------------- CSR build ----------------
__global__ void k_count(const int* __restrict__ dst, int E, int* __restrict__ deg) {
    int e = blockIdx.x * blockDim.x + threadIdx.x;
    if (e < E) atomicAdd(&deg[dst[e]], 1);
}

__global__ void k_dinv(const int* __restrict__ deg, float* __restrict__ dinv, int N) {
    int v = blockIdx.x * blockDim.x + threadIdx.x;
    if (v < N) dinv[v] = rsqrtf((float)deg[v] + 1.0f);
}

__global__ __launch_bounds__(1024) void k_scan(const int* __restrict__ deg, int* __restrict__ row_ptr,
                                               int* __restrict__ cursor, int N) {
    __shared__ int part[1024];
    int tid = threadIdx.x;
    int C = (N + 1023) >> 10;
    int s0 = tid * C;
    int s1 = min(s0 + C, N);
    int s = 0;
    for (int i = s0; i < s1; ++i) s += deg[i];
    part[tid] = s;
    __syncthreads();
    for (int off = 1; off < 1024; off <<= 1) {
        int v = (tid >= off) ? part[tid - off] : 0;
        __syncthreads();
        part[tid] += v;
        __syncthreads();
    }
    int base = (tid == 0) ? 0 : part[tid - 1];
    for (int i = s0; i < s1; ++i) {
        row_ptr[i] = base;
        cursor[i] = base;
        base += deg[i];
    }
    if (tid == 1023) row_ptr[N] = base;
}

// dst-range-filtered fill: writes land in an L2-resident window of col
__global__ void k_fill_range(const int* __restrict__ src, const int* __restrict__ dst, int E,
                             int* __restrict__ cursor, int* __restrict__ col, int lo, int hi) {
    int e = blockIdx.x * blockDim.x + threadIdx.x;
    if (e < E) {
        int d = dst[e];
        if (d >= lo && d < hi) {
            int p = atomicAdd(&cursor[d], 1);
            col[p] = src[e];
        }
    }
}

// ---------------- weight prep ----------------
// LSTM Wcat (512,192) -> bf16 hi/lo, row-major [gatecol][k]
__global__ void k_wprep(const float* __restrict__ W_ih, const float* __restrict__ W_hh,
                        unsigned short* __restrict__ whi, unsigned short* __restrict__ wlo) {
    int i = blockIdx.x * 256 + threadIdx.x;
    if (i >= 512 * 192) return;
    int g = i / 192, k = i - g * 192;
    float wv = (k < 64) ? W_ih[g * 64 + k] : W_hh[g * 128 + (k - 64)];
    unsigned short h, l;
    bsplit(wv, h, l);
    whi[i] = h;
    wlo[i] = l;
}

// W2 (64,64) -> transposed bf16 hi/lo [col][k]
__global__ void k_w2prep(const float* __restrict__ W2,
                         unsigned short* __restrict__ w2thi, unsigned short* __restrict__ w2tlo) {
    int i = blockIdx.x * 256 + threadIdx.x;
    if (i >= 64 * 64) return;
    int c = i >> 6, k = i & 63;
    unsigned short h, l;
    bsplit(W2[k * 64 + c], h, l);
    w2thi[c * 64 + k] = h;
    w2tlo[c * 64 + k] = l;
}

// ---------------- layer-1 aggregation at width 16 ----------------
__global__ __launch_bounds__(256) void k_agg16(const float* __restrict__ x, const float* __restrict__ dinv,
                                               const int* __restrict__ row_ptr, const int* __restrict__ col,
                                               float* __restrict__ u, int N) {
    int lane = threadIdx.x & 63;
    int v = blockIdx.x * 4 + (threadIdx.x >> 6);
    if (v >= N) return;
    int chan = lane & 15;
    int grp = lane >> 4;
    int b = row_ptr[v];
    int e = row_ptr[v + 1];
    float s = 0.f;
    for (int i = b + grp; i < e; i += 4) {
        int c = col[i];
        s = fmaf(dinv[c], x[(size_t)c * 16 + chan], s);
    }
    s += __shfl_xor(s, 16, 64);
    s += __shfl_xor(s, 32, 64);
    float dv = dinv[v];
    float tot = dv * fmaf(dv, x[(size_t)v * 16 + chan], s);
    if (lane < 16) u[(size_t)v * 16 + chan] = tot;
}

// ---------------- h1' = dinv * relu(u @ W1 + b1), stored bf16 ----------------
__global__ __launch_bounds__(256) void k_h1(const float* __restrict__ u, const float* __restrict__ W1,
                                            const float* __restrict__ b1, const float* __restrict__ dinv,
                                            unsigned short* __restrict__ h1bf, int N) {
    __shared__ float w[16 * 64];
    int tid = threadIdx.x;
    ((float4*)w)[tid] = ((const float4*)W1)[tid];
    __syncthreads();
    int h = tid & 63;
    int rg = __builtin_amdgcn_readfirstlane(tid >> 6);
    int v0 = blockIdx.x * 16 + rg * 4;
    float bv = b1[h];
#pragma unroll
    for (int r = 0; r < 4; ++r) {
        int v = v0 + r;
        if (v < N) {
            const float4* xr = (const float4*)(u + (size_t)v * 16);
            float4 xa = xr[0], xb = xr[1], xc = xr[2], xd = xr[3];
            float a = bv;
            a = fmaf(xa.x, w[0 * 64 + h], a);  a = fmaf(xa.y, w[1 * 64 + h], a);
            a = fmaf(xa.z, w[2 * 64 + h], a);  a = fmaf(xa.w, w[3 * 64 + h], a);
            a = fmaf(xb.x, w[4 * 64 + h], a);  a = fmaf(xb.y, w[5 * 64 + h], a);
            a = fmaf(xb.z, w[6 * 64 + h], a);  a = fmaf(xb.w, w[7 * 64 + h], a);
            a = fmaf(xc.x, w[8 * 64 + h], a);  a = fmaf(xc.y, w[9 * 64 + h], a);
            a = fmaf(xc.z, w[10 * 64 + h], a); a = fmaf(xc.w, w[11 * 64 + h], a);
            a = fmaf(xd.x, w[12 * 64 + h], a); a = fmaf(xd.y, w[13 * 64 + h], a);
            a = fmaf(xd.z, w[14 * 64 + h], a); a = fmaf(xd.w, w[15 * 64 + h], a);
            float r1 = fmaxf(a, 0.f) * dinv[v];
            h1bf[(size_t)v * 64 + h] = (unsigned short)bfr(r1);
        }
    }
}

// ---------------- fused: layer-2 gather -> h2 MFMA -> LSTM MFMA ----------------
// block = 256 (4 waves), 64-row tile. LDS staging: rows 64 x 392 B (hi + lo),
// K layout kc0..3 = h2(64), kc4..11 = h_prev(128).
// Phase 0: gather v -> kc8..11; stage h_prev[0..63] -> kc4..7.
// Phase 1: h2 = relu(v@W2+b2) via bf16x3 MFMA (A from kc8..11) -> kc0..3.
// Phase 2: stage h_prev[64..127] -> kc8..11 (v is dead).
// Phase 3: LSTM gates via bf16x3 MFMA over kc0..11, gating epilogue.
__global__ __launch_bounds__(256, 2) void k_fused(const unsigned short* __restrict__ h1bf,
                                                  const float* __restrict__ dinv,
                                                  const int* __restrict__ row_ptr, const int* __restrict__ col,
                                                  const unsigned short* __restrict__ w2thi,
                                                  const unsigned short* __restrict__ w2tlo,
                                                  const float* __restrict__ b2,
                                                  unsigned* __restrict__ hbuf, float* __restrict__ cbuf,
                                                  const unsigned short* __restrict__ whi,
                                                  const unsigned short* __restrict__ wlo,
                                                  const float* __restrict__ b_ih, const float* __restrict__ b_hh,
                                                  int N) {
    __shared__ __align__(16) char lds_hi[64 * 392];
    __shared__ __align__(16) char lds_lo[64 * 392];
    int tid = threadIdx.x;
    int lane = tid & 63;
    int w = tid >> 6;
    int row0 = blockIdx.x * 64;
    int l31 = lane & 31;
    int hf = lane >> 5;

    // ---- phase 0a: layer-2 gather (wave w handles 16 nodes serially) ----
    {
        const unsigned* tbl = (const unsigned*)h1bf;
        for (int t = 0; t < 16; ++t) {
            int m = w * 16 + t;
            int v = row0 + m;
            if (v < N) {
                int b = row_ptr[v], e = row_ptr[v + 1];
                float s0 = 0.f, s1 = 0.f;
                for (int i = b + hf; i < e; i += 2) {
                    int c = col[i];
                    unsigned pw = tbl[(size_t)c * 32 + l31];
                    s0 += bf2f((unsigned short)(pw & 0xffffu));
                    s1 += bf2f((unsigned short)(pw >> 16));
                }
                s0 += __shfl_xor(s0, 32, 64);
                s1 += __shfl_xor(s1, 32, 64);
                if (hf == 0) {
                    unsigned sw = tbl[(size_t)v * 32 + l31];
                    float dv = dinv[v];
                    float t0 = dv * (s0 + bf2f((unsigned short)(sw & 0xffffu)));
                    float t1 = dv * (s1 + bf2f((unsigned short)(sw >> 16)));
                    unsigned short h0, l0, h1v, l1v;
                    bsplit(t0, h0, l0);
                    bsplit(t1, h1v, l1v);
                    size_t bo = (size_t)m * 392 + 256 + (size_t)l31 * 4;
                    *(unsigned*)(lds_hi + bo) = (unsigned)h0 | ((unsigned)h1v << 16);
                    *(unsigned*)(lds_lo + bo) = (unsigned)l0 | ((unsigned)l1v << 16);
                }
            }
        }
    }
    // ---- phase 0b: stage h_prev cols 0..63 -> kc4..7 ----
    for (int idx = tid; idx < 64 * 16; idx += 256) {
        int m = idx >> 4;
        int c4 = (idx & 15) * 4;
        int row = row0 + m;
        uint4 pv = make_uint4(0, 0, 0, 0);
        if (row < N) pv = *(const uint4*)(hbuf + (size_t)row * 128 + c4);
        u64 hq = (u64)(pv.x & 0xffffu) | ((u64)(pv.y & 0xffffu) << 16) |
                 ((u64)(pv.z & 0xffffu) << 32) | ((u64)(pv.w & 0xffffu) << 48);
        u64 lq = (u64)(pv.x >> 16) | ((u64)(pv.y >> 16) << 16) |
                 ((u64)(pv.z >> 16) << 32) | ((u64)(pv.w >> 16) << 48);
        size_t bo = (size_t)m * 392 + 128 + (size_t)c4 * 2;
        *(u64*)(lds_hi + bo) = hq;
        *(u64*)(lds_lo + bo) = lq;
    }
    __syncthreads();

    // ---- phase 1: h2 = relu(v @ W2 + b2), one 32x32 MFMA tile per wave ----
    {
        int rowsub = w & 1, colsub = w >> 1;
        int c = colsub * 32 + l31;
        f32x16 acc;
#pragma unroll
        for (int r = 0; r < 16; ++r) acc[r] = 0.f;
        const char* ah = lds_hi + (size_t)(rowsub * 32 + l31) * 392 + 256 + (size_t)hf * 16;
        const char* al = lds_lo + (size_t)(rowsub * 32 + l31) * 392 + 256 + (size_t)hf * 16;
        const char* bh = (const char*)w2thi + (size_t)c * 128 + (size_t)hf * 16;
        const char* bl = (const char*)w2tlo + (size_t)c * 128 + (size_t)hf * 16;
#pragma unroll
        for (int kc = 0; kc < 4; ++kc) {
            AF Ahi, Alo, Bhi, Blo;
            Ahi.q[0] = *(const u64*)(ah + kc * 32); Ahi.q[1] = *(const u64*)(ah + kc * 32 + 8);
            Alo.q[0] = *(const u64*)(al + kc * 32); Alo.q[1] = *(const u64*)(al + kc * 32 + 8);
            Bhi.v = *(const s16x8*)(bh + kc * 32);
            Blo.v = *(const s16x8*)(bl + kc * 32);
            acc = __builtin_amdgcn_mfma_f32_32x32x16_bf16(Ahi.v, Bhi.v, acc, 0, 0, 0);
            acc = __builtin_amdgcn_mfma_f32_32x32x16_bf16(Alo.v, Bhi.v, acc, 0, 0, 0);
            acc = __builtin_amdgcn_mfma_f32_32x32x16_bf16(Ahi.v, Blo.v, acc, 0, 0, 0);
        }
        float bv = b2[c];
#pragma unroll
        for (int r = 0; r < 16; ++r) {
            int rl = (r & 3) + 8 * (r >> 2) + 4 * hf;
            int m = rowsub * 32 + rl;
            float val = fmaxf(acc[r] + bv, 0.f);
            unsigned short hh, ll;
            bsplit(val, hh, ll);
            size_t bo = (size_t)m * 392 + (size_t)c * 2;
            *(unsigned short*)(lds_hi + bo) = hh;
            *(unsigned short*)(lds_lo + bo) = ll;
        }
    }
    __syncthreads();

    // ---- phase 2: stage h_prev cols 64..127 -> kc8..11 ----
    for (int idx = tid; idx < 64 * 16; idx += 256) {
        int m = idx >> 4;
        int c4 = (idx & 15) * 4 + 64;
        int row = row0 + m;
        uint4 pv = make_uint4(0, 0, 0, 0);
        if (row < N) pv = *(const uint4*)(hbuf + (size_t)row * 128 + c4);
        u64 hq = (u64)(pv.x & 0xffffu) | ((u64)(pv.y & 0xffffu) << 16) |
                 ((u64)(pv.z & 0xffffu) << 32) | ((u64)(pv.w & 0xffffu) << 48);
        u64 lq = (u64)(pv.x >> 16) | ((u64)(pv.y >> 16) << 16) |
                 ((u64)(pv.z >> 16) << 32) | ((u64)(pv.w >> 16) << 48);
        size_t bo = (size_t)m * 392 + 256 + (size_t)(c4 - 64) * 2;
        *(u64*)(lds_hi + bo) = hq;
        *(u64*)(lds_lo + bo) = lq;
    }
    __syncthreads();

    // ---- phase 3: LSTM gates (wave w = col group) ----
    int col_j = w * 32 + l31;
    f32x16 acc[2][4];
#pragma unroll
    for (int s = 0; s < 2; ++s)
#pragma unroll
        for (int g = 0; g < 4; ++g)
#pragma unroll
            for (int r = 0; r < 16; ++r) acc[s][g][r] = 0.f;

    const char* whc = (const char*)whi;
    const char* wlc = (const char*)wlo;
    size_t bbase[4];
#pragma unroll
    for (int g = 0; g < 4; ++g) bbase[g] = (size_t)(g * 128 + col_j) * 384 + (size_t)hf * 16;
    size_t abase0 = (size_t)l31 * 392 + (size_t)hf * 16;
    size_t abase1 = (size_t)(32 + l31) * 392 + (size_t)hf * 16;

#pragma unroll
    for (int kc = 0; kc < 12; ++kc) {
        AF ahi0, alo0, ahi1, alo1;
        size_t a0 = abase0 + (size_t)kc * 32;
        size_t a1 = abase1 + (size_t)kc * 32;
        ahi0.q[0] = *(const u64*)(lds_hi + a0); ahi0.q[1] = *(const u64*)(lds_hi + a0 + 8);
        alo0.q[0] = *(const u64*)(lds_lo + a0); alo0.q[1] = *(const u64*)(lds_lo + a0 + 8);
        ahi1.q[0] = *(const u64*)(lds_hi + a1); ahi1.q[1] = *(const u64*)(lds_hi + a1 + 8);
        alo1.q[0] = *(const u64*)(lds_lo + a1); alo1.q[1] = *(const u64*)(lds_lo + a1 + 8);
        AF bhi[4], blo[4];
#pragma unroll
        for (int g = 0; g < 4; ++g) {
            size_t bo = bbase[g] + (size_t)kc * 32;
            bhi[g].v = *(const s16x8*)(whc + bo);
            blo[g].v = *(const s16x8*)(wlc + bo);
        }
#pragma unroll
        for (int g = 0; g < 4; ++g) {
            acc[0][g] = __builtin_amdgcn_mfma_f32_32x32x16_bf16(ahi0.v, bhi[g].v, acc[0][g], 0, 0, 0);
            acc[0][g] = __builtin_amdgcn_mfma_f32_32x32x16_bf16(alo0.v, bhi[g].v, acc[0][g], 0, 0, 0);
            acc[0][g] = __builtin_amdgcn_mfma_f32_32x32x16_bf16(ahi0.v, blo[g].v, acc[0][g], 0, 0, 0);
            acc[1][g] = __builtin_amdgcn_mfma_f32_32x32x16_bf16(ahi1.v, bhi[g].v, acc[1][g], 0, 0, 0);
            acc[1][g] = __builtin_amdgcn_mfma_f32_32x32x16_bf16(alo1.v, bhi[g].v, acc[1][g], 0, 0, 0);
            acc[1][g] = __builtin_amdgcn_mfma_f32_32x32x16_bf16(ahi1.v, blo[g].v, acc[1][g], 0, 0, 0);
        }
    }

    float bi = b_ih[col_j] + b_hh[col_j];
    float bff = b_ih[128 + col_j] + b_hh[128 + col_j];
    float bg = b_ih[256 + col_j] + b_hh[256 + col_j];
    float bo = b_ih[384 + col_j] + b_hh[384 + col_j];
#pragma unroll
    for (int s = 0; s < 2; ++s) {
#pragma unroll
        for (int r = 0; r < 16; ++r) {
            int rl = (r & 3) + 8 * (r >> 2) + 4 * hf;
            int row = row0 + s * 32 + rl;
            if (row < N) {
                size_t off = (size_t)row * 128 + col_j;
                float iv = sigf(acc[s][0][r] + bi);
                float fv = sigf(acc[s][1][r] + bff);
                float gv = tanhfast(acc[s][2][r] + bg);
                float ov = sigf(acc[s][3][r] + bo);
                float cnew = fmaf(fv, cbuf[off], iv * gv);
                float hnew = ov * tanhfast(cnew);
                cbuf[off] = cnew;
                unsigned short hh, hl;
                bsplit(hnew, hh, hl);
                hbuf[off] = (unsigned)hh | ((unsigned)hl << 16);
            }
        }
    }
}

// ---------------- MLP head (hbuf is packed bf16 hi|lo) ----------------
__global__ __launch_bounds__(256) void k_mlp(const unsigned* __restrict__ hbuf, const float* __restrict__ Wf1,
                                             const float* __restrict__ bf1, const float* __restrict__ Wf2,
                                             const float* __restrict__ bf2, float* __restrict__ out, int N) {
    int lane = threadIdx.x & 63;
    int v = blockIdx.x * 4 + (threadIdx.x >> 6);
    if (v >= N) return;
    int j = lane & 31;
    int half = lane >> 5;
    const unsigned* hr = hbuf + (size_t)v * 128 + half * 64;
    float s = 0.f;
#pragma unroll
    for (int k = 0; k < 64; ++k) {
        unsigned pw = hr[k];
        float hv = bf2f((unsigned short)(pw & 0xffffu)) + bf2f((unsigned short)(pw >> 16));
        s = fmaf(hv, Wf1[(half * 64 + k) * 32 + j], s);
    }
    s += __shfl_down(s, 32, 64);
    float z = fmaxf(s + bf1[j], 0.f);
    float p = z * Wf2[j];
#pragma unroll
    for (int off = 16; off > 0; off >>= 1) p += __shfl_down(p, off, 64);
    if (lane == 0) out[v] = p + bf2[0];
}

extern "C" void kernel_launch(void* const* d_in, const int* in_sizes, int n_in,
                              void* d_out, int out_size, void* d_ws, size_t ws_size,
                              hipStream_t stream) {
    const float* x_seq = (const float*)d_in[0];
    const int* eidx = (const int*)d_in[1];
    const float* W1 = (const float*)d_in[2];
    const float* b1 = (const float*)d_in[3];
    const float* W2 = (const float*)d_in[4];
    const float* b2 = (const float*)d_in[5];
    const float* W_ih = (const float*)d_in[6];
    const float* W_hh = (const float*)d_in[7];
    const float* b_ih = (const float*)d_in[8];
    const float* b_hh = (const float*)d_in[9];
    const float* Wf1 = (const float*)d_in[10];
    const float* bf1 = (const float*)d_in[11];
    const float* Wf2 = (const float*)d_in[12];
    const float* bf2 = (const float*)d_in[13];

    int N = out_size;                 // 50000
    int E = in_sizes[1] / 2;          // 1,600,000
    int T = in_sizes[0] / (N * 16);   // 24
    const int* srcp = eidx;
    const int* dstp = eidx + E;

    char* ws = (char*)d_ws;
    size_t off = 0;
    auto alloc = [&](size_t bytes) -> char* {
        char* p = ws + off;
        off = (off + bytes + 255) & ~(size_t)255;
        return p;
    };
    int* deg = (int*)alloc((size_t)N * 4);
    int* row_ptr = (int*)alloc(((size_t)N + 1) * 4);
    int* cursor = (int*)alloc((size_t)N * 4);
    int* col = (int*)alloc((size_t)E * 4);
    float* dinv = (float*)alloc((size_t)N * 4);
    float* ubuf = (float*)alloc((size_t)N * 16 * 4);
    unsigned short* h1bf = (unsigned short*)alloc((size_t)N * 64 * 2);
    unsigned* hbuf = (unsigned*)alloc((size_t)N * 128 * 4);
    float* cbuf = (float*)alloc((size_t)N * 128 * 4);
    unsigned short* whi = (unsigned short*)alloc((size_t)512 * 192 * 2);
    unsigned short* wlo = (unsigned short*)alloc((size_t)512 * 192 * 2);
    unsigned short* w2thi = (unsigned short*)alloc((size_t)64 * 64 * 2);
    unsigned short* w2tlo = (unsigned short*)alloc((size_t)64 * 64 * 2);

    hipMemsetAsync(deg, 0, (size_t)N * 4, stream);
    hipMemsetAsync(hbuf, 0, (size_t)N * 128 * 4, stream);
    hipMemsetAsync(cbuf, 0, (size_t)N * 128 * 4, stream);

    k_count<<<(E + 255) / 256, 256, 0, stream>>>(dstp, E, deg);
    k_dinv<<<(N + 255) / 256, 256, 0, stream>>>(deg, dinv, N);
    k_scan<<<1, 1024, 0, stream>>>(deg, row_ptr, cursor, N);
    int halfN = N / 2;
    k_fill_range<<<(E + 255) / 256, 256, 0, stream>>>(srcp, dstp, E, cursor, col, 0, halfN);
    k_fill_range<<<(E + 255) / 256, 256, 0, stream>>>(srcp, dstp, E, cursor, col, halfN, N);
    k_wprep<<<(512 * 192 + 255) / 256, 256, 0, stream>>>(W_ih, W_hh, whi, wlo);
    k_w2prep<<<(64 * 64 + 255) / 256, 256, 0, stream>>>(W2, w2thi, w2tlo);

    int node_wave_blocks = (N + 3) / 4;
    int gemm_blocks = (N + 15) / 16;
    int fused_blocks = (N + 63) / 64;
    for (int t = 0; t < T; ++t) {
        const float* xt = x_seq + (size_t)t * N * 16;
        k_agg16<<<node_wave_blocks, 256, 0, stream>>>(xt, dinv, row_ptr, col, ubuf, N);
        k_h1<<<gemm_blocks, 256, 0, stream>>>(ubuf, W1, b1, dinv, h1bf, N);
        k_fused<<<fused_blocks, 256, 0, stream>>>(h1bf, dinv, row_ptr, col, w2thi, w2tlo, b2,
                                                  hbuf, cbuf, whi, wlo, b_ih, b_hh, N);
    }
    k_mlp<<<node_wave_blocks, 256, 0, stream>>>(hbuf, Wf1, bf1, Wf2, bf2, (float*)d_out, N);
}

// Round 5
// 5459.348 us; speedup vs baseline: 1.8188x; 1.8188x over previous
//
#include <hip/hip_runtime.h>
#include <hip/hip_bf16.h>
#include <math.h>

// SpatialTemporalModel: GCN(2-layer) x24 -> LSTM(128) -> MLP head.
// Round 5: de-fuse the layer-2 gather (round-4 regression: serial gather at
// 19% occupancy starved the MFMA kernel). Structure now:
//   k_gcn1  : layer-1 gather + h1 GEMM in-wave (u never hits HBM)
//   k_agg64p: wave-per-node layer-2 gather -> packed (hi|lo) v
//   k_h2lstm: LDS-stage v+h_prev -> h2 bf16x3 MFMA -> LSTM bf16x3 MFMA -> gate
// Gather kernels keep 50000-wave TLP; MFMA kernel keeps LDS fusion.

typedef short s16x8 __attribute__((ext_vector_type(8)));
typedef float f32x16 __attribute__((ext_vector_type(16)));
typedef unsigned long long u64;
union AF { s16x8 v; u64 q[2]; };

__device__ __forceinline__ float sigf(float x) { return 1.f / (1.f + __expf(-x)); }
__device__ __forceinline__ float tanhfast(float x) { return 1.f - 2.f / (1.f + __expf(2.f * x)); }

// round-to-nearest-even f32 -> bf16 bits
__device__ __forceinline__ unsigned bfr(float x) {
    union { float f; unsigned u; } c; c.f = x;
    return (c.u + 0x7fffu + ((c.u >> 16) & 1u)) >> 16;
}
__device__ __forceinline__ void bsplit(float x, unsigned short& hi, unsigned short& lo) {
    unsigned h = bfr(x);
    union { unsigned u; float f; } hf; hf.u = h << 16;
    hi = (unsigned short)h;
    lo = (unsigned short)bfr(x - hf.f);
}
__device__ __forceinline__ float bf2f(unsigned short b) {
    union { unsigned u; float f; } c; c.u = ((unsigned)b) << 16;
    return c.f;
}

// ---------------- CSR build ----------------
__global__ void k_count(const int* __restrict__ dst, int E, int* __restrict__ deg) {
    int e = blockIdx.x * blockDim.x + threadIdx.x;
    if (e < E) atomicAdd(&deg[dst[e]], 1);
}

__global__ void k_dinv(const int* __restrict__ deg, float* __restrict__ dinv, int N) {
    int v = blockIdx.x * blockDim.x + threadIdx.x;
    if (v < N) dinv[v] = rsqrtf((float)deg[v] + 1.0f);
}

__global__ __launch_bounds__(1024) void k_scan(const int* __restrict__ deg, int* __restrict__ row_ptr,
                                               int* __restrict__ cursor, int N) {
    __shared__ int part[1024];
    int tid = threadIdx.x;
    int C = (N + 1023) >> 10;
    int s0 = tid * C;
    int s1 = min(s0 + C, N);
    int s = 0;
    for (int i = s0; i < s1; ++i) s += deg[i];
    part[tid] = s;
    __syncthreads();
    for (int off = 1; off < 1024; off <<= 1) {
        int v = (tid >= off) ? part[tid - off] : 0;
        __syncthreads();
        part[tid] += v;
        __syncthreads();
    }
    int base = (tid == 0) ? 0 : part[tid - 1];
    for (int i = s0; i < s1; ++i) {
        row_ptr[i] = base;
        cursor[i] = base;
        base += deg[i];
    }
    if (tid == 1023) row_ptr[N] = base;
}

// dst-range-filtered fill: writes land in an L2-resident window of col
__global__ void k_fill_range(const int* __restrict__ src, const int* __restrict__ dst, int E,
                             int* __restrict__ cursor, int* __restrict__ col, int lo, int hi) {
    int e = blockIdx.x * blockDim.x + threadIdx.x;
    if (e < E) {
        int d = dst[e];
        if (d >= lo && d < hi) {
            int p = atomicAdd(&cursor[d], 1);
            col[p] = src[e];
        }
    }
}

// ---------------- weight prep ----------------
// LSTM Wcat (512,192) -> bf16 hi/lo, row-major [gatecol][k] (k: 0..63 = h2/x, 64..191 = h_prev)
__global__ void k_wprep(const float* __restrict__ W_ih, const float* __restrict__ W_hh,
                        unsigned short* __restrict__ whi, unsigned short* __restrict__ wlo) {
    int i = blockIdx.x * 256 + threadIdx.x;
    if (i >= 512 * 192) return;
    int g = i / 192, k = i - g * 192;
    float wv = (k < 64) ? W_ih[g * 64 + k] : W_hh[g * 128 + (k - 64)];
    unsigned short h, l;
    bsplit(wv, h, l);
    whi[i] = h;
    wlo[i] = l;
}

// W2 (64,64) -> transposed bf16 hi/lo [col][k]
__global__ void k_w2prep(const float* __restrict__ W2,
                         unsigned short* __restrict__ w2thi, unsigned short* __restrict__ w2tlo) {
    int i = blockIdx.x * 256 + threadIdx.x;
    if (i >= 64 * 64) return;
    int c = i >> 6, k = i & 63;
    unsigned short h, l;
    bsplit(W2[k * 64 + c], h, l);
    w2thi[c * 64 + k] = h;
    w2tlo[c * 64 + k] = l;
}

// ---------------- fused layer-1: agg16 + h1 GEMM in-wave ----------------
// wave per node. Gather phase: lane=(grp,chan) 4-way edge split x 16 channels.
// After xor-reduction every lane holds u[lane&15]; h1[lane] then needs 16
// shfl+fma. h1' = dinv * relu(u @ W1 + b1) written bf16 (128B/wave coalesced).
__global__ __launch_bounds__(256) void k_gcn1(const float* __restrict__ x, const float* __restrict__ dinv,
                                              const int* __restrict__ row_ptr, const int* __restrict__ col,
                                              const float* __restrict__ W1, const float* __restrict__ b1,
                                              unsigned short* __restrict__ h1bf, int N) {
    __shared__ float w[16 * 64];
    int tid = threadIdx.x;
    ((float4*)w)[tid] = ((const float4*)W1)[tid];
    __syncthreads();
    int lane = tid & 63;
    int v = blockIdx.x * 4 + (tid >> 6);
    if (v >= N) return;
    int chan = lane & 15;
    int grp = lane >> 4;
    int b = row_ptr[v];
    int e = row_ptr[v + 1];
    float s = 0.f;
    for (int i = b + grp; i < e; i += 4) {
        int c = col[i];
        s = fmaf(dinv[c], x[(size_t)c * 16 + chan], s);
    }
    s += __shfl_xor(s, 16, 64);
    s += __shfl_xor(s, 32, 64);
    float dv = dinv[v];
    float u = dv * fmaf(dv, x[(size_t)v * 16 + chan], s);
    // h1: lane computes output channel = lane
    float a = b1[lane];
#pragma unroll
    for (int k = 0; k < 16; ++k) {
        float uk = __shfl(u, k, 16);
        a = fmaf(uk, w[k * 64 + lane], a);  // bank = lane%32: 2-way alias, free
    }
    float r1 = fmaxf(a, 0.f) * dv;
    h1bf[(size_t)v * 64 + lane] = (unsigned short)bfr(r1);
}

// ---------------- layer-2 aggregation -> packed (hi|lo) v ----------------
// wave per node; lane=(half, chanpair): 32 u32 lanes cover 64 bf16 channels,
// halves split the edge list 2-way. Output: u32 per channel = bf16hi | bf16lo<<16.
__global__ __launch_bounds__(256) void k_agg64p(const unsigned short* __restrict__ h1bf,
                                                const float* __restrict__ dinv,
                                                const int* __restrict__ row_ptr, const int* __restrict__ col,
                                                unsigned* __restrict__ vpack, int N) {
    int lane = threadIdx.x & 63;
    int v = blockIdx.x * 4 + (threadIdx.x >> 6);
    if (v >= N) return;
    int cp = lane & 31;
    int half = lane >> 5;
    int b = row_ptr[v];
    int e = row_ptr[v + 1];
    float s0 = 0.f, s1 = 0.f;
    const unsigned* tbl = (const unsigned*)h1bf;
    for (int i = b + half; i < e; i += 2) {
        int c = col[i];
        unsigned w = tbl[(size_t)c * 32 + cp];
        s0 += bf2f((unsigned short)(w & 0xffffu));
        s1 += bf2f((unsigned short)(w >> 16));
    }
    s0 += __shfl_xor(s0, 32, 64);
    s1 += __shfl_xor(s1, 32, 64);
    if (half == 0) {
        unsigned sw = tbl[(size_t)v * 32 + cp];
        float dv = dinv[v];
        float t0 = dv * (s0 + bf2f((unsigned short)(sw & 0xffffu)));
        float t1 = dv * (s1 + bf2f((unsigned short)(sw >> 16)));
        unsigned short h0, l0, h1v, l1v;
        bsplit(t0, h0, l0);
        bsplit(t1, h1v, l1v);
        uint2 o;
        o.x = (unsigned)h0 | ((unsigned)l0 << 16);
        o.y = (unsigned)h1v | ((unsigned)l1v << 16);
        ((uint2*)(vpack + (size_t)v * 64))[cp] = o;
    }
}

// ---------------- fused h2 MFMA + LSTM MFMA ----------------
// block = 256 (4 waves), 64-row tile. LDS: 64 rows x 392 B (hi + lo planes).
// K layout: kc0..3 = h2(64ch), kc4..11 = h_prev(128ch).
// Phase 0: stage v (packed) -> kc8..11; h_prev cols 0..63 -> kc4..7.
// Phase 1: h2 = relu(v@W2+b2) via bf16x3 MFMA (A from kc8..11) -> kc0..3.
// Phase 2: h_prev cols 64..127 -> kc8..11 (v dead).
// Phase 3: LSTM gates via bf16x3 MFMA over kc0..11 + gating epilogue.
__global__ __launch_bounds__(256, 2) void k_h2lstm(const unsigned* __restrict__ vpack,
                                                   const unsigned short* __restrict__ w2thi,
                                                   const unsigned short* __restrict__ w2tlo,
                                                   const float* __restrict__ b2,
                                                   unsigned* __restrict__ hbuf, float* __restrict__ cbuf,
                                                   const unsigned short* __restrict__ whi,
                                                   const unsigned short* __restrict__ wlo,
                                                   const float* __restrict__ b_ih, const float* __restrict__ b_hh,
                                                   int N) {
    __shared__ __align__(16) char lds_hi[64 * 392];
    __shared__ __align__(16) char lds_lo[64 * 392];
    int tid = threadIdx.x;
    int lane = tid & 63;
    int w = tid >> 6;
    int row0 = blockIdx.x * 64;
    int l31 = lane & 31;
    int hf = lane >> 5;

    // ---- phase 0a: stage packed v -> kc8..11 ----
    for (int idx = tid; idx < 64 * 16; idx += 256) {
        int m = idx >> 4;
        int c4 = (idx & 15) * 4;
        int row = row0 + m;
        uint4 pv = make_uint4(0, 0, 0, 0);
        if (row < N) pv = *(const uint4*)(vpack + (size_t)row * 64 + c4);
        u64 hq = (u64)(pv.x & 0xffffu) | ((u64)(pv.y & 0xffffu) << 16) |
                 ((u64)(pv.z & 0xffffu) << 32) | ((u64)(pv.w & 0xffffu) << 48);
        u64 lq = (u64)(pv.x >> 16) | ((u64)(pv.y >> 16) << 16) |
                 ((u64)(pv.z >> 16) << 32) | ((u64)(pv.w >> 16) << 48);
        size_t bo = (size_t)m * 392 + 256 + (size_t)c4 * 2;
        *(u64*)(lds_hi + bo) = hq;
        *(u64*)(lds_lo + bo) = lq;
    }
    // ---- phase 0b: stage h_prev cols 0..63 -> kc4..7 ----
    for (int idx = tid; idx < 64 * 16; idx += 256) {
        int m = idx >> 4;
        int c4 = (idx & 15) * 4;
        int row = row0 + m;
        uint4 pv = make_uint4(0, 0, 0, 0);
        if (row < N) pv = *(const uint4*)(hbuf + (size_t)row * 128 + c4);
        u64 hq = (u64)(pv.x & 0xffffu) | ((u64)(pv.y & 0xffffu) << 16) |
                 ((u64)(pv.z & 0xffffu) << 32) | ((u64)(pv.w & 0xffffu) << 48);
        u64 lq = (u64)(pv.x >> 16) | ((u64)(pv.y >> 16) << 16) |
                 ((u64)(pv.z >> 16) << 32) | ((u64)(pv.w >> 16) << 48);
        size_t bo = (size_t)m * 392 + 128 + (size_t)c4 * 2;
        *(u64*)(lds_hi + bo) = hq;
        *(u64*)(lds_lo + bo) = lq;
    }
    __syncthreads();

    // ---- phase 1: h2 = relu(v @ W2 + b2), one 32x32 tile per wave ----
    {
        int rowsub = w & 1, colsub = w >> 1;
        int c = colsub * 32 + l31;
        f32x16 acc;
#pragma unroll
        for (int r = 0; r < 16; ++r) acc[r] = 0.f;
        const char* ah = lds_hi + (size_t)(rowsub * 32 + l31) * 392 + 256 + (size_t)hf * 16;
        const char* al = lds_lo + (size_t)(rowsub * 32 + l31) * 392 + 256 + (size_t)hf * 16;
        const char* bh = (const char*)w2thi + (size_t)c * 128 + (size_t)hf * 16;
        const char* bl = (const char*)w2tlo + (size_t)c * 128 + (size_t)hf * 16;
#pragma unroll
        for (int kc = 0; kc < 4; ++kc) {
            AF Ahi, Alo, Bhi, Blo;
            Ahi.q[0] = *(const u64*)(ah + kc * 32); Ahi.q[1] = *(const u64*)(ah + kc * 32 + 8);
            Alo.q[0] = *(const u64*)(al + kc * 32); Alo.q[1] = *(const u64*)(al + kc * 32 + 8);
            Bhi.v = *(const s16x8*)(bh + kc * 32);
            Blo.v = *(const s16x8*)(bl + kc * 32);
            acc = __builtin_amdgcn_mfma_f32_32x32x16_bf16(Ahi.v, Bhi.v, acc, 0, 0, 0);
            acc = __builtin_amdgcn_mfma_f32_32x32x16_bf16(Alo.v, Bhi.v, acc, 0, 0, 0);
            acc = __builtin_amdgcn_mfma_f32_32x32x16_bf16(Ahi.v, Blo.v, acc, 0, 0, 0);
        }
        float bv = b2[c];
#pragma unroll
        for (int r = 0; r < 16; ++r) {
            int rl = (r & 3) + 8 * (r >> 2) + 4 * hf;
            int m = rowsub * 32 + rl;
            float val = fmaxf(acc[r] + bv, 0.f);
            unsigned short hh, ll;
            bsplit(val, hh, ll);
            size_t bo = (size_t)m * 392 + (size_t)c * 2;
            *(unsigned short*)(lds_hi + bo) = hh;
            *(unsigned short*)(lds_lo + bo) = ll;
        }
    }
    __syncthreads();

    // ---- phase 2: stage h_prev cols 64..127 -> kc8..11 ----
    for (int idx = tid; idx < 64 * 16; idx += 256) {
        int m = idx >> 4;
        int c4 = (idx & 15) * 4 + 64;
        int row = row0 + m;
        uint4 pv = make_uint4(0, 0, 0, 0);
        if (row < N) pv = *(const uint4*)(hbuf + (size_t)row * 128 + c4);
        u64 hq = (u64)(pv.x & 0xffffu) | ((u64)(pv.y & 0xffffu) << 16) |
                 ((u64)(pv.z & 0xffffu) << 32) | ((u64)(pv.w & 0xffffu) << 48);
        u64 lq = (u64)(pv.x >> 16) | ((u64)(pv.y >> 16) << 16) |
                 ((u64)(pv.z >> 16) << 32) | ((u64)(pv.w >> 16) << 48);
        size_t bo = (size_t)m * 392 + 256 + (size_t)(c4 - 64) * 2;
        *(u64*)(lds_hi + bo) = hq;
        *(u64*)(lds_lo + bo) = lq;
    }
    __syncthreads();

    // ---- phase 3: LSTM gates (wave w = col group, owns all 4 gates) ----
    int col_j = w * 32 + l31;
    f32x16 acc[2][4];
#pragma unroll
    for (int s = 0; s < 2; ++s)
#pragma unroll
        for (int g = 0; g < 4; ++g)
#pragma unroll
            for (int r = 0; r < 16; ++r) acc[s][g][r] = 0.f;

    const char* whc = (const char*)whi;
    const char* wlc = (const char*)wlo;
    size_t bbase[4];
#pragma unroll
    for (int g = 0; g < 4; ++g) bbase[g] = (size_t)(g * 128 + col_j) * 384 + (size_t)hf * 16;
    size_t abase0 = (size_t)l31 * 392 + (size_t)hf * 16;
    size_t abase1 = (size_t)(32 + l31) * 392 + (size_t)hf * 16;

#pragma unroll
    for (int kc = 0; kc < 12; ++kc) {
        AF ahi0, alo0, ahi1, alo1;
        size_t a0 = abase0 + (size_t)kc * 32;
        size_t a1 = abase1 + (size_t)kc * 32;
        ahi0.q[0] = *(const u64*)(lds_hi + a0); ahi0.q[1] = *(const u64*)(lds_hi + a0 + 8);
        alo0.q[0] = *(const u64*)(lds_lo + a0); alo0.q[1] = *(const u64*)(lds_lo + a0 + 8);
        ahi1.q[0] = *(const u64*)(lds_hi + a1); ahi1.q[1] = *(const u64*)(lds_hi + a1 + 8);
        alo1.q[0] = *(const u64*)(lds_lo + a1); alo1.q[1] = *(const u64*)(lds_lo + a1 + 8);
        AF bhi[4], blo[4];
#pragma unroll
        for (int g = 0; g < 4; ++g) {
            size_t bo = bbase[g] + (size_t)kc * 32;
            bhi[g].v = *(const s16x8*)(whc + bo);
            blo[g].v = *(const s16x8*)(wlc + bo);
        }
#pragma unroll
        for (int g = 0; g < 4; ++g) {
            acc[0][g] = __builtin_amdgcn_mfma_f32_32x32x16_bf16(ahi0.v, bhi[g].v, acc[0][g], 0, 0, 0);
            acc[0][g] = __builtin_amdgcn_mfma_f32_32x32x16_bf16(alo0.v, bhi[g].v, acc[0][g], 0, 0, 0);
            acc[0][g] = __builtin_amdgcn_mfma_f32_32x32x16_bf16(ahi0.v, blo[g].v, acc[0][g], 0, 0, 0);
            acc[1][g] = __builtin_amdgcn_mfma_f32_32x32x16_bf16(ahi1.v, bhi[g].v, acc[1][g], 0, 0, 0);
            acc[1][g] = __builtin_amdgcn_mfma_f32_32x32x16_bf16(alo1.v, bhi[g].v, acc[1][g], 0, 0, 0);
            acc[1][g] = __builtin_amdgcn_mfma_f32_32x32x16_bf16(ahi1.v, blo[g].v, acc[1][g], 0, 0, 0);
        }
    }

    float bi = b_ih[col_j] + b_hh[col_j];
    float bff = b_ih[128 + col_j] + b_hh[128 + col_j];
    float bg = b_ih[256 + col_j] + b_hh[256 + col_j];
    float bo = b_ih[384 + col_j] + b_hh[384 + col_j];
#pragma unroll
    for (int s = 0; s < 2; ++s) {
#pragma unroll
        for (int r = 0; r < 16; ++r) {
            int rl = (r & 3) + 8 * (r >> 2) + 4 * hf;
            int row = row0 + s * 32 + rl;
            if (row < N) {
                size_t off = (size_t)row * 128 + col_j;
                float iv = sigf(acc[s][0][r] + bi);
                float fv = sigf(acc[s][1][r] + bff);
                float gv = tanhfast(acc[s][2][r] + bg);
                float ov = sigf(acc[s][3][r] + bo);
                float cnew = fmaf(fv, cbuf[off], iv * gv);
                float hnew = ov * tanhfast(cnew);
                cbuf[off] = cnew;
                unsigned short hh, hl;
                bsplit(hnew, hh, hl);
                hbuf[off] = (unsigned)hh | ((unsigned)hl << 16);
            }
        }
    }
}

// ---------------- MLP head (hbuf is packed bf16 hi|lo) ----------------
__global__ __launch_bounds__(256) void k_mlp(const unsigned* __restrict__ hbuf, const float* __restrict__ Wf1,
                                             const float* __restrict__ bf1, const float* __restrict__ Wf2,
                                             const float* __restrict__ bf2, float* __restrict__ out, int N) {
    int lane = threadIdx.x & 63;
    int v = blockIdx.x * 4 + (threadIdx.x >> 6);
    if (v >= N) return;
    int j = lane & 31;
    int half = lane >> 5;
    const unsigned* hr = hbuf + (size_t)v * 128 + half * 64;
    float s = 0.f;
#pragma unroll
    for (int k = 0; k < 64; ++k) {
        unsigned pw = hr[k];
        float hv = bf2f((unsigned short)(pw & 0xffffu)) + bf2f((unsigned short)(pw >> 16));
        s = fmaf(hv, Wf1[(half * 64 + k) * 32 + j], s);
    }
    s += __shfl_down(s, 32, 64);
    float z = fmaxf(s + bf1[j], 0.f);
    float p = z * Wf2[j];
#pragma unroll
    for (int off = 16; off > 0; off >>= 1) p += __shfl_down(p, off, 64);
    if (lane == 0) out[v] = p + bf2[0];
}

extern "C" void kernel_launch(void* const* d_in, const int* in_sizes, int n_in,
                              void* d_out, int out_size, void* d_ws, size_t ws_size,
                              hipStream_t stream) {
    const float* x_seq = (const float*)d_in[0];
    const int* eidx = (const int*)d_in[1];
    const float* W1 = (const float*)d_in[2];
    const float* b1 = (const float*)d_in[3];
    const float* W2 = (const float*)d_in[4];
    const float* b2 = (const float*)d_in[5];
    const float* W_ih = (const float*)d_in[6];
    const float* W_hh = (const float*)d_in[7];
    const float* b_ih = (const float*)d_in[8];
    const float* b_hh = (const float*)d_in[9];
    const float* Wf1 = (const float*)d_in[10];
    const float* bf1 = (const float*)d_in[11];
    const float* Wf2 = (const float*)d_in[12];
    const float* bf2 = (const float*)d_in[13];

    int N = out_size;                 // 50000
    int E = in_sizes[1] / 2;          // 1,600,000
    int T = in_sizes[0] / (N * 16);   // 24
    const int* srcp = eidx;
    const int* dstp = eidx + E;

    char* ws = (char*)d_ws;
    size_t off = 0;
    auto alloc = [&](size_t bytes) -> char* {
        char* p = ws + off;
        off = (off + bytes + 255) & ~(size_t)255;
        return p;
    };
    int* deg = (int*)alloc((size_t)N * 4);
    int* row_ptr = (int*)alloc(((size_t)N + 1) * 4);
    int* cursor = (int*)alloc((size_t)N * 4);
    int* col = (int*)alloc((size_t)E * 4);
    float* dinv = (float*)alloc((size_t)N * 4);
    unsigned short* h1bf = (unsigned short*)alloc((size_t)N * 64 * 2);
    unsigned* vpack = (unsigned*)alloc((size_t)N * 64 * 4);
    unsigned* hbuf = (unsigned*)alloc((size_t)N * 128 * 4);
    float* cbuf = (float*)alloc((size_t)N * 128 * 4);
    unsigned short* whi = (unsigned short*)alloc((size_t)512 * 192 * 2);
    unsigned short* wlo = (unsigned short*)alloc((size_t)512 * 192 * 2);
    unsigned short* w2thi = (unsigned short*)alloc((size_t)64 * 64 * 2);
    unsigned short* w2tlo = (unsigned short*)alloc((size_t)64 * 64 * 2);

    hipMemsetAsync(deg, 0, (size_t)N * 4, stream);
    hipMemsetAsync(hbuf, 0, (size_t)N * 128 * 4, stream);
    hipMemsetAsync(cbuf, 0, (size_t)N * 128 * 4, stream);

    k_count<<<(E + 255) / 256, 256, 0, stream>>>(dstp, E, deg);
    k_dinv<<<(N + 255) / 256, 256, 0, stream>>>(deg, dinv, N);
    k_scan<<<1, 1024, 0, stream>>>(deg, row_ptr, cursor, N);
    int halfN = N / 2;
    k_fill_range<<<(E + 255) / 256, 256, 0, stream>>>(srcp, dstp, E, cursor, col, 0, halfN);
    k_fill_range<<<(E + 255) / 256, 256, 0, stream>>>(srcp, dstp, E, cursor, col, halfN, N);
    k_wprep<<<(512 * 192 + 255) / 256, 256, 0, stream>>>(W_ih, W_hh, whi, wlo);
    k_w2prep<<<(64 * 64 + 255) / 256, 256, 0, stream>>>(W2, w2thi, w2tlo);

    int node_wave_blocks = (N + 3) / 4;
    int tile_blocks = (N + 63) / 64;
    for (int t = 0; t < T; ++t) {
        const float* xt = x_seq + (size_t)t * N * 16;
        k_gcn1<<<node_wave_blocks, 256, 0, stream>>>(xt, dinv, row_ptr, col, W1, b1, h1bf, N);
        k_agg64p<<<node_wave_blocks, 256, 0, stream>>>(h1bf, dinv, row_ptr, col, vpack, N);
        k_h2lstm<<<tile_blocks, 256, 0, stream>>>(vpack, w2thi, w2tlo, b2, hbuf, cbuf,
                                                  whi, wlo, b_ih, b_hh, N);
    }
    k_mlp<<<node_wave_blocks, 256, 0, stream>>>(hbuf, Wf1, bf1, Wf2, bf2, (float*)d_out, N);
}

// Round 6
// 4112.020 us; speedup vs baseline: 2.4148x; 1.3277x over previous
//
#include <hip/hip_runtime.h>
#include <hip/hip_bf16.h>
#include <math.h>

// SpatialTemporalModel: GCN(2-layer) x24 -> LSTM(128) -> MLP head.
// Round 6: (a) single-block k_scan (111us on one CU) -> 3-kernel hierarchical
// scan (~10us); (b) gather kernels restructured for edge-ILP: k_gcn1 8-way
// edges x float2 loads (u parked in per-wave LDS for the h1 GEMM), k_agg64p
// 4-way edges x uint2 loads, both with unroll-2 to double outstanding loads.
// k_h2lstm (h2 MFMA + LSTM MFMA in LDS) unchanged from round 5.

typedef short s16x8 __attribute__((ext_vector_type(8)));
typedef float f32x16 __attribute__((ext_vector_type(16)));
typedef unsigned long long u64;
union AF { s16x8 v; u64 q[2]; };

__device__ __forceinline__ float sigf(float x) { return 1.f / (1.f + __expf(-x)); }
__device__ __forceinline__ float tanhfast(float x) { return 1.f - 2.f / (1.f + __expf(2.f * x)); }

// round-to-nearest-even f32 -> bf16 bits
__device__ __forceinline__ unsigned bfr(float x) {
    union { float f; unsigned u; } c; c.f = x;
    return (c.u + 0x7fffu + ((c.u >> 16) & 1u)) >> 16;
}
__device__ __forceinline__ void bsplit(float x, unsigned short& hi, unsigned short& lo) {
    unsigned h = bfr(x);
    union { unsigned u; float f; } hf; hf.u = h << 16;
    hi = (unsigned short)h;
    lo = (unsigned short)bfr(x - hf.f);
}
__device__ __forceinline__ float bf2f(unsigned short b) {
    union { unsigned u; float f; } c; c.u = ((unsigned)b) << 16;
    return c.f;
}

// ---------------- CSR build ----------------
__global__ void k_count(const int* __restrict__ dst, int E, int* __restrict__ deg) {
    int e = blockIdx.x * blockDim.x + threadIdx.x;
    if (e < E) atomicAdd(&deg[dst[e]], 1);
}

__global__ void k_dinv(const int* __restrict__ deg, float* __restrict__ dinv, int N) {
    int v = blockIdx.x * blockDim.x + threadIdx.x;
    if (v < N) dinv[v] = rsqrtf((float)deg[v] + 1.0f);
}

// hierarchical scan, stage 1: per-block (256-elem) sums
__global__ __launch_bounds__(256) void k_scan_part(const int* __restrict__ deg, int* __restrict__ partial, int N) {
    int tid = threadIdx.x;
    int i = blockIdx.x * 256 + tid;
    int v = (i < N) ? deg[i] : 0;
    int s = v;
#pragma unroll
    for (int off = 1; off < 64; off <<= 1) s += __shfl_xor(s, off, 64);
    __shared__ int ws[4];
    if ((tid & 63) == 0) ws[tid >> 6] = s;
    __syncthreads();
    if (tid == 0) partial[blockIdx.x] = ws[0] + ws[1] + ws[2] + ws[3];
}

// stage 2: exclusive scan of <=256 partials, in place
__global__ __launch_bounds__(256) void k_scan_top(int* __restrict__ partial, int nb) {
    __shared__ int sm[256];
    int t = threadIdx.x;
    int x = (t < nb) ? partial[t] : 0;
    sm[t] = x;
    __syncthreads();
#pragma unroll
    for (int off = 1; off < 256; off <<= 1) {
        int y = (t >= off) ? sm[t - off] : 0;
        __syncthreads();
        sm[t] += y;
        __syncthreads();
    }
    if (t < nb) partial[t] = sm[t] - x;  // exclusive
}

// stage 3: block-local exclusive scan + block offset -> row_ptr, cursor
__global__ __launch_bounds__(256) void k_scan_fill(const int* __restrict__ deg, const int* __restrict__ partial,
                                                   int* __restrict__ row_ptr, int* __restrict__ cursor, int N) {
    int tid = threadIdx.x;
    int lane = tid & 63;
    int wv = tid >> 6;
    int i = blockIdx.x * 256 + tid;
    int v = (i < N) ? deg[i] : 0;
    int incl = v;
#pragma unroll
    for (int off = 1; off < 64; off <<= 1) {
        int y = __shfl_up(incl, off, 64);
        if (lane >= off) incl += y;
    }
    __shared__ int ws[4];
    if (lane == 63) ws[wv] = incl;
    __syncthreads();
    int woff = 0;
    for (int w = 0; w < wv; ++w) woff += ws[w];
    int excl = incl - v + woff + partial[blockIdx.x];
    if (i < N) {
        row_ptr[i] = excl;
        cursor[i] = excl;
        if (i == N - 1) row_ptr[N] = excl + v;
    }
}

// dst-range-filtered fill: writes land in an L2-resident window of col
__global__ void k_fill_range(const int* __restrict__ src, const int* __restrict__ dst, int E,
                             int* __restrict__ cursor, int* __restrict__ col, int lo, int hi) {
    int e = blockIdx.x * blockDim.x + threadIdx.x;
    if (e < E) {
        int d = dst[e];
        if (d >= lo && d < hi) {
            int p = atomicAdd(&cursor[d], 1);
            col[p] = src[e];
        }
    }
}

// ---------------- weight prep ----------------
// LSTM Wcat (512,192) -> bf16 hi/lo, row-major [gatecol][k] (k: 0..63 = h2, 64..191 = h_prev)
__global__ void k_wprep(const float* __restrict__ W_ih, const float* __restrict__ W_hh,
                        unsigned short* __restrict__ whi, unsigned short* __restrict__ wlo) {
    int i = blockIdx.x * 256 + threadIdx.x;
    if (i >= 512 * 192) return;
    int g = i / 192, k = i - g * 192;
    float wv = (k < 64) ? W_ih[g * 64 + k] : W_hh[g * 128 + (k - 64)];
    unsigned short h, l;
    bsplit(wv, h, l);
    whi[i] = h;
    wlo[i] = l;
}

// W2 (64,64) -> transposed bf16 hi/lo [col][k]
__global__ void k_w2prep(const float* __restrict__ W2,
                         unsigned short* __restrict__ w2thi, unsigned short* __restrict__ w2tlo) {
    int i = blockIdx.x * 256 + threadIdx.x;
    if (i >= 64 * 64) return;
    int c = i >> 6, k = i & 63;
    unsigned short h, l;
    bsplit(W2[k * 64 + c], h, l);
    w2thi[c * 64 + k] = h;
    w2tlo[c * 64 + k] = l;
}

// ---------------- fused layer-1: agg16 + h1 GEMM in-wave ----------------
// wave per node. Gather: lane=(eg 8, cg 8): 8-way edge split, float2 channel
// loads (channels 2cg, 2cg+1). Reduction xor 8/16/32; u parked in per-wave LDS;
// h1[lane] = relu(u @ W1 + b1)[lane] * dinv, written bf16 (128B/wave coalesced).
__global__ __launch_bounds__(256) void k_gcn1(const float* __restrict__ x, const float* __restrict__ dinv,
                                              const int* __restrict__ row_ptr, const int* __restrict__ col,
                                              const float* __restrict__ W1, const float* __restrict__ b1,
                                              unsigned short* __restrict__ h1bf, int N) {
    __shared__ float w[16 * 64];
    __shared__ float uu[4][16];
    int tid = threadIdx.x;
    ((float4*)w)[tid] = ((const float4*)W1)[tid];
    __syncthreads();
    int lane = tid & 63;
    int wv = tid >> 6;
    int v = blockIdx.x * 4 + wv;
    if (v >= N) return;
    int cg = lane & 7;   // channel pair: 2cg, 2cg+1
    int eg = lane >> 3;  // 8 edge groups
    int b = row_ptr[v];
    int e = row_ptr[v + 1];
    float s0 = 0.f, s1 = 0.f;
#pragma unroll 2
    for (int i = b + eg; i < e; i += 8) {
        int c = col[i];
        float2 xv = *(const float2*)(x + (size_t)c * 16 + 2 * cg);
        float dc = dinv[c];
        s0 = fmaf(dc, xv.x, s0);
        s1 = fmaf(dc, xv.y, s1);
    }
    s0 += __shfl_xor(s0, 8, 64);  s1 += __shfl_xor(s1, 8, 64);
    s0 += __shfl_xor(s0, 16, 64); s1 += __shfl_xor(s1, 16, 64);
    s0 += __shfl_xor(s0, 32, 64); s1 += __shfl_xor(s1, 32, 64);
    float dv = dinv[v];
    if (eg == 0) {
        float2 xv = *(const float2*)(x + (size_t)v * 16 + 2 * cg);
        uu[wv][2 * cg]     = dv * fmaf(dv, xv.x, s0);
        uu[wv][2 * cg + 1] = dv * fmaf(dv, xv.y, s1);
    }
    // same-wave LDS producer->consumer: hardware lgkmcnt orders it, no barrier
    float a = b1[lane];
#pragma unroll
    for (int k = 0; k < 16; ++k)
        a = fmaf(uu[wv][k], w[k * 64 + lane], a);  // w bank = lane%32: 2-way, free
    float r1 = fmaxf(a, 0.f) * dv;
    h1bf[(size_t)v * 64 + lane] = (unsigned short)bfr(r1);
}

// ---------------- layer-2 aggregation -> packed (hi|lo) v ----------------
// wave per node; lane=(eg 4, cp 16): 4-way edge split, uint2 loads (channels
// 4cp..4cp+3). Output u32 per channel = bf16hi | bf16lo<<16, uint4 stores.
__global__ __launch_bounds__(256) void k_agg64p(const unsigned short* __restrict__ h1bf,
                                                const float* __restrict__ dinv,
                                                const int* __restrict__ row_ptr, const int* __restrict__ col,
                                                unsigned* __restrict__ vpack, int N) {
    int lane = threadIdx.x & 63;
    int v = blockIdx.x * 4 + (threadIdx.x >> 6);
    if (v >= N) return;
    int cp = lane & 15;  // uint2 index: channels 4cp..4cp+3
    int eg = lane >> 4;  // 4 edge groups
    int b = row_ptr[v];
    int e = row_ptr[v + 1];
    float s0 = 0.f, s1 = 0.f, s2 = 0.f, s3 = 0.f;
    const uint2* tbl = (const uint2*)h1bf;  // row = 16 uint2
#pragma unroll 2
    for (int i = b + eg; i < e; i += 4) {
        int c = col[i];
        uint2 pw = tbl[(size_t)c * 16 + cp];
        s0 += bf2f((unsigned short)(pw.x & 0xffffu));
        s1 += bf2f((unsigned short)(pw.x >> 16));
        s2 += bf2f((unsigned short)(pw.y & 0xffffu));
        s3 += bf2f((unsigned short)(pw.y >> 16));
    }
    s0 += __shfl_xor(s0, 16, 64); s1 += __shfl_xor(s1, 16, 64);
    s2 += __shfl_xor(s2, 16, 64); s3 += __shfl_xor(s3, 16, 64);
    s0 += __shfl_xor(s0, 32, 64); s1 += __shfl_xor(s1, 32, 64);
    s2 += __shfl_xor(s2, 32, 64); s3 += __shfl_xor(s3, 32, 64);
    if (eg == 0) {
        uint2 sw = tbl[(size_t)v * 16 + cp];
        float dv = dinv[v];
        float t0 = dv * (s0 + bf2f((unsigned short)(sw.x & 0xffffu)));
        float t1 = dv * (s1 + bf2f((unsigned short)(sw.x >> 16)));
        float t2 = dv * (s2 + bf2f((unsigned short)(sw.y & 0xffffu)));
        float t3 = dv * (s3 + bf2f((unsigned short)(sw.y >> 16)));
        unsigned short h0, l0, h1v, l1v, h2v, l2v, h3, l3;
        bsplit(t0, h0, l0); bsplit(t1, h1v, l1v);
        bsplit(t2, h2v, l2v); bsplit(t3, h3, l3);
        uint4 o;
        o.x = (unsigned)h0 | ((unsigned)l0 << 16);
        o.y = (unsigned)h1v | ((unsigned)l1v << 16);
        o.z = (unsigned)h2v | ((unsigned)l2v << 16);
        o.w = (unsigned)h3 | ((unsigned)l3 << 16);
        ((uint4*)(vpack + (size_t)v * 64))[cp] = o;
    }
}

// ---------------- fused h2 MFMA + LSTM MFMA ----------------
// block = 256 (4 waves), 64-row tile. LDS: 64 rows x 392 B (hi + lo planes).
// K layout: kc0..3 = h2(64ch), kc4..11 = h_prev(128ch).
__global__ __launch_bounds__(256, 2) void k_h2lstm(const unsigned* __restrict__ vpack,
                                                   const unsigned short* __restrict__ w2thi,
                                                   const unsigned short* __restrict__ w2tlo,
                                                   const float* __restrict__ b2,
                                                   unsigned* __restrict__ hbuf, float* __restrict__ cbuf,
                                                   const unsigned short* __restrict__ whi,
                                                   const unsigned short* __restrict__ wlo,
                                                   const float* __restrict__ b_ih, const float* __restrict__ b_hh,
                                                   int N) {
    __shared__ __align__(16) char lds_hi[64 * 392];
    __shared__ __align__(16) char lds_lo[64 * 392];
    int tid = threadIdx.x;
    int lane = tid & 63;
    int w = tid >> 6;
    int row0 = blockIdx.x * 64;
    int l31 = lane & 31;
    int hf = lane >> 5;

    // ---- phase 0a: stage packed v -> kc8..11 ----
    for (int idx = tid; idx < 64 * 16; idx += 256) {
        int m = idx >> 4;
        int c4 = (idx & 15) * 4;
        int row = row0 + m;
        uint4 pv = make_uint4(0, 0, 0, 0);
        if (row < N) pv = *(const uint4*)(vpack + (size_t)row * 64 + c4);
        u64 hq = (u64)(pv.x & 0xffffu) | ((u64)(pv.y & 0xffffu) << 16) |
                 ((u64)(pv.z & 0xffffu) << 32) | ((u64)(pv.w & 0xffffu) << 48);
        u64 lq = (u64)(pv.x >> 16) | ((u64)(pv.y >> 16) << 16) |
                 ((u64)(pv.z >> 16) << 32) | ((u64)(pv.w >> 16) << 48);
        size_t bo = (size_t)m * 392 + 256 + (size_t)c4 * 2;
        *(u64*)(lds_hi + bo) = hq;
        *(u64*)(lds_lo + bo) = lq;
    }
    // ---- phase 0b: stage h_prev cols 0..63 -> kc4..7 ----
    for (int idx = tid; idx < 64 * 16; idx += 256) {
        int m = idx >> 4;
        int c4 = (idx & 15) * 4;
        int row = row0 + m;
        uint4 pv = make_uint4(0, 0, 0, 0);
        if (row < N) pv = *(const uint4*)(hbuf + (size_t)row * 128 + c4);
        u64 hq = (u64)(pv.x & 0xffffu) | ((u64)(pv.y & 0xffffu) << 16) |
                 ((u64)(pv.z & 0xffffu) << 32) | ((u64)(pv.w & 0xffffu) << 48);
        u64 lq = (u64)(pv.x >> 16) | ((u64)(pv.y >> 16) << 16) |
                 ((u64)(pv.z >> 16) << 32) | ((u64)(pv.w >> 16) << 48);
        size_t bo = (size_t)m * 392 + 128 + (size_t)c4 * 2;
        *(u64*)(lds_hi + bo) = hq;
        *(u64*)(lds_lo + bo) = lq;
    }
    __syncthreads();

    // ---- phase 1: h2 = relu(v @ W2 + b2), one 32x32 tile per wave ----
    {
        int rowsub = w & 1, colsub = w >> 1;
        int c = colsub * 32 + l31;
        f32x16 acc;
#pragma unroll
        for (int r = 0; r < 16; ++r) acc[r] = 0.f;
        const char* ah = lds_hi + (size_t)(rowsub * 32 + l31) * 392 + 256 + (size_t)hf * 16;
        const char* al = lds_lo + (size_t)(rowsub * 32 + l31) * 392 + 256 + (size_t)hf * 16;
        const char* bh = (const char*)w2thi + (size_t)c * 128 + (size_t)hf * 16;
        const char* bl = (const char*)w2tlo + (size_t)c * 128 + (size_t)hf * 16;
#pragma unroll
        for (int kc = 0; kc < 4; ++kc) {
            AF Ahi, Alo, Bhi, Blo;
            Ahi.q[0] = *(const u64*)(ah + kc * 32); Ahi.q[1] = *(const u64*)(ah + kc * 32 + 8);
            Alo.q[0] = *(const u64*)(al + kc * 32); Alo.q[1] = *(const u64*)(al + kc * 32 + 8);
            Bhi.v = *(const s16x8*)(bh + kc * 32);
            Blo.v = *(const s16x8*)(bl + kc * 32);
            acc = __builtin_amdgcn_mfma_f32_32x32x16_bf16(Ahi.v, Bhi.v, acc, 0, 0, 0);
            acc = __builtin_amdgcn_mfma_f32_32x32x16_bf16(Alo.v, Bhi.v, acc, 0, 0, 0);
            acc = __builtin_amdgcn_mfma_f32_32x32x16_bf16(Ahi.v, Blo.v, acc, 0, 0, 0);
        }
        float bv = b2[c];
#pragma unroll
        for (int r = 0; r < 16; ++r) {
            int rl = (r & 3) + 8 * (r >> 2) + 4 * hf;
            int m = rowsub * 32 + rl;
            float val = fmaxf(acc[r] + bv, 0.f);
            unsigned short hh, ll;
            bsplit(val, hh, ll);
            size_t bo = (size_t)m * 392 + (size_t)c * 2;
            *(unsigned short*)(lds_hi + bo) = hh;
            *(unsigned short*)(lds_lo + bo) = ll;
        }
    }
    __syncthreads();

    // ---- phase 2: stage h_prev cols 64..127 -> kc8..11 (v dead) ----
    for (int idx = tid; idx < 64 * 16; idx += 256) {
        int m = idx >> 4;
        int c4 = (idx & 15) * 4 + 64;
        int row = row0 + m;
        uint4 pv = make_uint4(0, 0, 0, 0);
        if (row < N) pv = *(const uint4*)(hbuf + (size_t)row * 128 + c4);
        u64 hq = (u64)(pv.x & 0xffffu) | ((u64)(pv.y & 0xffffu) << 16) |
                 ((u64)(pv.z & 0xffffu) << 32) | ((u64)(pv.w & 0xffffu) << 48);
        u64 lq = (u64)(pv.x >> 16) | ((u64)(pv.y >> 16) << 16) |
                 ((u64)(pv.z >> 16) << 32) | ((u64)(pv.w >> 16) << 48);
        size_t bo = (size_t)m * 392 + 256 + (size_t)(c4 - 64) * 2;
        *(u64*)(lds_hi + bo) = hq;
        *(u64*)(lds_lo + bo) = lq;
    }
    __syncthreads();

    // ---- phase 3: LSTM gates (wave w = col group, owns all 4 gates) ----
    int col_j = w * 32 + l31;
    f32x16 acc[2][4];
#pragma unroll
    for (int s = 0; s < 2; ++s)
#pragma unroll
        for (int g = 0; g < 4; ++g)
#pragma unroll
            for (int r = 0; r < 16; ++r) acc[s][g][r] = 0.f;

    const char* whc = (const char*)whi;
    const char* wlc = (const char*)wlo;
    size_t bbase[4];
#pragma unroll
    for (int g = 0; g < 4; ++g) bbase[g] = (size_t)(g * 128 + col_j) * 384 + (size_t)hf * 16;
    size_t abase0 = (size_t)l31 * 392 + (size_t)hf * 16;
    size_t abase1 = (size_t)(32 + l31) * 392 + (size_t)hf * 16;

#pragma unroll
    for (int kc = 0; kc < 12; ++kc) {
        AF ahi0, alo0, ahi1, alo1;
        size_t a0 = abase0 + (size_t)kc * 32;
        size_t a1 = abase1 + (size_t)kc * 32;
        ahi0.q[0] = *(const u64*)(lds_hi + a0); ahi0.q[1] = *(const u64*)(lds_hi + a0 + 8);
        alo0.q[0] = *(const u64*)(lds_lo + a0); alo0.q[1] = *(const u64*)(lds_lo + a0 + 8);
        ahi1.q[0] = *(const u64*)(lds_hi + a1); ahi1.q[1] = *(const u64*)(lds_hi + a1 + 8);
        alo1.q[0] = *(const u64*)(lds_lo + a1); alo1.q[1] = *(const u64*)(lds_lo + a1 + 8);
        AF bhi[4], blo[4];
#pragma unroll
        for (int g = 0; g < 4; ++g) {
            size_t bo = bbase[g] + (size_t)kc * 32;
            bhi[g].v = *(const s16x8*)(whc + bo);
            blo[g].v = *(const s16x8*)(wlc + bo);
        }
#pragma unroll
        for (int g = 0; g < 4; ++g) {
            acc[0][g] = __builtin_amdgcn_mfma_f32_32x32x16_bf16(ahi0.v, bhi[g].v, acc[0][g], 0, 0, 0);
            acc[0][g] = __builtin_amdgcn_mfma_f32_32x32x16_bf16(alo0.v, bhi[g].v, acc[0][g], 0, 0, 0);
            acc[0][g] = __builtin_amdgcn_mfma_f32_32x32x16_bf16(ahi0.v, blo[g].v, acc[0][g], 0, 0, 0);
            acc[1][g] = __builtin_amdgcn_mfma_f32_32x32x16_bf16(ahi1.v, bhi[g].v, acc[1][g], 0, 0, 0);
            acc[1][g] = __builtin_amdgcn_mfma_f32_32x32x16_bf16(alo1.v, bhi[g].v, acc[1][g], 0, 0, 0);
            acc[1][g] = __builtin_amdgcn_mfma_f32_32x32x16_bf16(ahi1.v, blo[g].v, acc[1][g], 0, 0, 0);
        }
    }

    float bi = b_ih[col_j] + b_hh[col_j];
    float bff = b_ih[128 + col_j] + b_hh[128 + col_j];
    float bg = b_ih[256 + col_j] + b_hh[256 + col_j];
    float bo = b_ih[384 + col_j] + b_hh[384 + col_j];
#pragma unroll
    for (int s = 0; s < 2; ++s) {
#pragma unroll
        for (int r = 0; r < 16; ++r) {
            int rl = (r & 3) + 8 * (r >> 2) + 4 * hf;
            int row = row0 + s * 32 + rl;
            if (row < N) {
                size_t off = (size_t)row * 128 + col_j;
                float iv = sigf(acc[s][0][r] + bi);
                float fv = sigf(acc[s][1][r] + bff);
                float gv = tanhfast(acc[s][2][r] + bg);
                float ov = sigf(acc[s][3][r] + bo);
                float cnew = fmaf(fv, cbuf[off], iv * gv);
                float hnew = ov * tanhfast(cnew);
                cbuf[off] = cnew;
                unsigned short hh, hl;
                bsplit(hnew, hh, hl);
                hbuf[off] = (unsigned)hh | ((unsigned)hl << 16);
            }
        }
    }
}

// ---------------- MLP head (hbuf is packed bf16 hi|lo) ----------------
__global__ __launch_bounds__(256) void k_mlp(const unsigned* __restrict__ hbuf, const float* __restrict__ Wf1,
                                             const float* __restrict__ bf1, const float* __restrict__ Wf2,
                                             const float* __restrict__ bf2, float* __restrict__ out, int N) {
    int lane = threadIdx.x & 63;
    int v = blockIdx.x * 4 + (threadIdx.x >> 6);
    if (v >= N) return;
    int j = lane & 31;
    int half = lane >> 5;
    const unsigned* hr = hbuf + (size_t)v * 128 + half * 64;
    float s = 0.f;
#pragma unroll
    for (int k = 0; k < 64; ++k) {
        unsigned pw = hr[k];
        float hv = bf2f((unsigned short)(pw & 0xffffu)) + bf2f((unsigned short)(pw >> 16));
        s = fmaf(hv, Wf1[(half * 64 + k) * 32 + j], s);
    }
    s += __shfl_down(s, 32, 64);
    float z = fmaxf(s + bf1[j], 0.f);
    float p = z * Wf2[j];
#pragma unroll
    for (int off = 16; off > 0; off >>= 1) p += __shfl_down(p, off, 64);
    if (lane == 0) out[v] = p + bf2[0];
}

extern "C" void kernel_launch(void* const* d_in, const int* in_sizes, int n_in,
                              void* d_out, int out_size, void* d_ws, size_t ws_size,
                              hipStream_t stream) {
    const float* x_seq = (const float*)d_in[0];
    const int* eidx = (const int*)d_in[1];
    const float* W1 = (const float*)d_in[2];
    const float* b1 = (const float*)d_in[3];
    const float* W2 = (const float*)d_in[4];
    const float* b2 = (const float*)d_in[5];
    const float* W_ih = (const float*)d_in[6];
    const float* W_hh = (const float*)d_in[7];
    const float* b_ih = (const float*)d_in[8];
    const float* b_hh = (const float*)d_in[9];
    const float* Wf1 = (const float*)d_in[10];
    const float* bf1 = (const float*)d_in[11];
    const float* Wf2 = (const float*)d_in[12];
    const float* bf2 = (const float*)d_in[13];

    int N = out_size;                 // 50000
    int E = in_sizes[1] / 2;          // 1,600,000
    int T = in_sizes[0] / (N * 16);   // 24
    const int* srcp = eidx;
    const int* dstp = eidx + E;

    char* ws = (char*)d_ws;
    size_t off = 0;
    auto alloc = [&](size_t bytes) -> char* {
        char* p = ws + off;
        off = (off + bytes + 255) & ~(size_t)255;
        return p;
    };
    int* deg = (int*)alloc((size_t)N * 4);
    int* row_ptr = (int*)alloc(((size_t)N + 1) * 4);
    int* cursor = (int*)alloc((size_t)N * 4);
    int* col = (int*)alloc((size_t)E * 4);
    int* partial = (int*)alloc(260 * 4);
    float* dinv = (float*)alloc((size_t)N * 4);
    unsigned short* h1bf = (unsigned short*)alloc((size_t)N * 64 * 2);
    unsigned* vpack = (unsigned*)alloc((size_t)N * 64 * 4);
    unsigned* hbuf = (unsigned*)alloc((size_t)N * 128 * 4);
    float* cbuf = (float*)alloc((size_t)N * 128 * 4);
    unsigned short* whi = (unsigned short*)alloc((size_t)512 * 192 * 2);
    unsigned short* wlo = (unsigned short*)alloc((size_t)512 * 192 * 2);
    unsigned short* w2thi = (unsigned short*)alloc((size_t)64 * 64 * 2);
    unsigned short* w2tlo = (unsigned short*)alloc((size_t)64 * 64 * 2);

    hipMemsetAsync(deg, 0, (size_t)N * 4, stream);
    hipMemsetAsync(hbuf, 0, (size_t)N * 128 * 4, stream);
    hipMemsetAsync(cbuf, 0, (size_t)N * 128 * 4, stream);

    int nb = (N + 255) / 256;  // 196 <= 256
    k_count<<<(E + 255) / 256, 256, 0, stream>>>(dstp, E, deg);
    k_dinv<<<(N + 255) / 256, 256, 0, stream>>>(deg, dinv, N);
    k_scan_part<<<nb, 256, 0, stream>>>(deg, partial, N);
    k_scan_top<<<1, 256, 0, stream>>>(partial, nb);
    k_scan_fill<<<nb, 256, 0, stream>>>(deg, partial, row_ptr, cursor, N);
    int halfN = N / 2;
    k_fill_range<<<(E + 255) / 256, 256, 0, stream>>>(srcp, dstp, E, cursor, col, 0, halfN);
    k_fill_range<<<(E + 255) / 256, 256, 0, stream>>>(srcp, dstp, E, cursor, col, halfN, N);
    k_wprep<<<(512 * 192 + 255) / 256, 256, 0, stream>>>(W_ih, W_hh, whi, wlo);
    k_w2prep<<<(64 * 64 + 255) / 256, 256, 0, stream>>>(W2, w2thi, w2tlo);

    int node_wave_blocks = (N + 3) / 4;
    int tile_blocks = (N + 63) / 64;
    for (int t = 0; t < T; ++t) {
        const float* xt = x_seq + (size_t)t * N * 16;
        k_gcn1<<<node_wave_blocks, 256, 0, stream>>>(xt, dinv, row_ptr, col, W1, b1, h1bf, N);
        k_agg64p<<<node_wave_blocks, 256, 0, stream>>>(h1bf, dinv, row_ptr, col, vpack, N);
        k_h2lstm<<<tile_blocks, 256, 0, stream>>>(vpack, w2thi, w2tlo, b2, hbuf, cbuf,
                                                  whi, wlo, b_ih, b_hh, N);
    }
    k_mlp<<<node_wave_blocks, 256, 0, stream>>>(hbuf, Wf1, bf1, Wf2, bf2, (float*)d_out, N);
}